// Round 5
// baseline (1687.900 us; speedup 1.0000x reference)
//
#include <hip/hip_runtime.h>
#include <math.h>

#define B_    32
#define T_    512
#define WDIM_ 300
#define H_    256
#define G4_   1024            // 4*H
#define M_    (B_ * T_)       // 16384

// persistent-LSTM geometry: team = 8 WGs covering one batch-pair, BOTH dirs
#define NCG   8               // col groups per team (32 d's each)
#define NWG   128             // 16 batch-pairs * NCG   (both dirs per WG)
#define THR   512
#define HXN   (2 * 2 * B_ * H_)   // packets: [buf][dir][32][256]

// repeat macros -> compile-time-constant indices (SROA-safe register arrays)
#define RPT4(M, b)  M(b) M((b)+1) M((b)+2) M((b)+3)
#define RPT16(M, b) RPT4(M, b) RPT4(M, (b)+4) RPT4(M, (b)+8) RPT4(M, (b)+12)
#define RPT64(M)    RPT16(M, 0) RPT16(M, 16) RPT16(M, 32) RPT16(M, 48)

// fast gate math: v_exp_f32 + v_rcp_f32 (|rel err| ~1e-6, threshold 8e-4)
__device__ __forceinline__ float fsigm(float x) {
    return __builtin_amdgcn_rcpf(1.f + __expf(-x));
}
__device__ __forceinline__ float ftanh(float x) {
    const float ax = fabsf(x);
    const float t  = 1.f - 2.f * __builtin_amdgcn_rcpf(__expf(2.f * ax) + 1.f);
    return copysignf(t, x);
}

// ---------------------------------------------------------------------------
// Kernel 1: z = relu(emb[x] @ W_in + b_in)   [16384,300]@[300,256]
// ---------------------------------------------------------------------------
__global__ __launch_bounds__(256)
void k_embed_proj(const float* __restrict__ emb, const float* __restrict__ Win,
                  const float* __restrict__ bin, const int* __restrict__ x,
                  float* __restrict__ z)
{
    __shared__ float Ash[16][132];
    __shared__ float Bsh[16][132];
    __shared__ int   rows[128];

    const int tid = threadIdx.x;
    const int tx = tid & 15, ty = tid >> 4;
    const int rm = blockIdx.y * 128;
    const int cn = blockIdx.x * 128;

    if (tid < 128) rows[tid] = x[rm + tid];
    __syncthreads();

    float acc[8][8];
#pragma unroll
    for (int i = 0; i < 8; ++i)
#pragma unroll
        for (int j = 0; j < 8; ++j) acc[i][j] = 0.f;

    for (int kc = 0; kc < 19; ++kc) {
        const int k0 = kc * 16;
#pragma unroll
        for (int e = 0; e < 8; ++e) {
            const int idx = e * 256 + tid;
            const int r = idx >> 4, kk = idx & 15;
            const int k = k0 + kk;
            const int v = rows[r];
            Ash[kk][r] = (k < WDIM_) ? emb[(size_t)v * WDIM_ + k] : 0.f;
        }
#pragma unroll
        for (int e = 0; e < 8; ++e) {
            const int idx = e * 256 + tid;
            const int kk = idx >> 7, n = idx & 127;
            const int k = k0 + kk;
            Bsh[kk][n] = (k < WDIM_) ? Win[(size_t)k * H_ + cn + n] : 0.f;
        }
        __syncthreads();
#pragma unroll
        for (int kk = 0; kk < 16; ++kk) {
            float a[8], bb[8];
#pragma unroll
            for (int i = 0; i < 8; ++i) a[i] = Ash[kk][ty * 8 + i];
#pragma unroll
            for (int j = 0; j < 8; ++j) bb[j] = Bsh[kk][tx * 8 + j];
#pragma unroll
            for (int i = 0; i < 8; ++i)
#pragma unroll
                for (int j = 0; j < 8; ++j) acc[i][j] += a[i] * bb[j];
        }
        __syncthreads();
    }

#pragma unroll
    for (int i = 0; i < 8; ++i) {
        const int row = rm + ty * 8 + i;
#pragma unroll
        for (int j = 0; j < 8; ++j) {
            const int col = cn + tx * 8 + j;
            z[(size_t)row * H_ + col] = fmaxf(acc[i][j] + bin[col], 0.f);
        }
    }
}

// ---------------------------------------------------------------------------
// Kernel 2: P_d = z @ Wih_d + bl_d  (both directions via blockIdx.z)
// ---------------------------------------------------------------------------
__global__ __launch_bounds__(256)
void k_in_proj(const float* __restrict__ z,
               const float* __restrict__ Wf, const float* __restrict__ blf,
               const float* __restrict__ Wb, const float* __restrict__ blb,
               float* __restrict__ Pf, float* __restrict__ Pb)
{
    const float* W  = blockIdx.z ? Wb  : Wf;
    const float* bl = blockIdx.z ? blb : blf;
    float*       P  = blockIdx.z ? Pb  : Pf;

    __shared__ float Ash[16][132];
    __shared__ float Bsh[16][132];

    const int tid = threadIdx.x;
    const int tx = tid & 15, ty = tid >> 4;
    const int rm = blockIdx.y * 128;
    const int cn = blockIdx.x * 128;

    float acc[8][8];
#pragma unroll
    for (int i = 0; i < 8; ++i)
#pragma unroll
        for (int j = 0; j < 8; ++j) acc[i][j] = 0.f;

    for (int kc = 0; kc < 16; ++kc) {
        const int k0 = kc * 16;
#pragma unroll
        for (int e = 0; e < 8; ++e) {
            const int idx = e * 256 + tid;
            const int r = idx >> 4, kk = idx & 15;
            Ash[kk][r] = z[(size_t)(rm + r) * H_ + k0 + kk];
        }
#pragma unroll
        for (int e = 0; e < 8; ++e) {
            const int idx = e * 256 + tid;
            const int kk = idx >> 7, n = idx & 127;
            Bsh[kk][n] = W[(size_t)(k0 + kk) * G4_ + cn + n];
        }
        __syncthreads();
#pragma unroll
        for (int kk = 0; kk < 16; ++kk) {
            float a[8], bb[8];
#pragma unroll
            for (int i = 0; i < 8; ++i) a[i] = Ash[kk][ty * 8 + i];
#pragma unroll
            for (int j = 0; j < 8; ++j) bb[j] = Bsh[kk][tx * 8 + j];
#pragma unroll
            for (int i = 0; i < 8; ++i)
#pragma unroll
                for (int j = 0; j < 8; ++j) acc[i][j] += a[i] * bb[j];
        }
        __syncthreads();
    }

#pragma unroll
    for (int i = 0; i < 8; ++i) {
        const int row = rm + ty * 8 + i;
#pragma unroll
        for (int j = 0; j < 8; ++j) {
            const int col = cn + tx * 8 + j;
            P[(size_t)row * G4_ + col] = acc[i][j] + bl[col];
        }
    }
}

// ---------------------------------------------------------------------------
// Init: zero h packet buffers ({h=0, tag=0} == initial state)
// ---------------------------------------------------------------------------
__global__ void k_init(unsigned long long* __restrict__ hx)
{
    const int i = blockIdx.x * blockDim.x + threadIdx.x;
    if (i < HXN) hx[i] = 0ull;
}

// ---------------------------------------------------------------------------
// Kernel 3: persistent bidirectional LSTM, dir-interleaved, fence-free.
// WG = (batch-pair bg, colgroup cg of 32 d's), handling BOTH directions.
// Per round: poll/GEMV/gates/publish for dir0, then dir1 — each dir's packet
// round trip is hidden under the other dir's compute. Packets: {h,tag} 8-byte
// relaxed agent-scope atomics, parity double-buffered; teammates stride-16 in
// blockIdx (same XCD slot). Both dirs' Whh slices register-resident
// (64+64 floats/thread, constant indices).
// ---------------------------------------------------------------------------
__global__ __launch_bounds__(THR, 2)
void k_lstm_persist(const float* __restrict__ Pf, const float* __restrict__ Pb,
                    const float* __restrict__ Whf, const float* __restrict__ Whb,
                    const int* __restrict__ lengths,
                    unsigned long long* __restrict__ hx,
                    float* __restrict__ pool)
{
    __shared__ float h_sh[2][2][256];   // [dir][row][d]
    __shared__ float zp[2][4][2][128];  // [dir][ksplit][row][local gate-col]

    const int tid = threadIdx.x;
    const int wg  = blockIdx.x;
    const int bg  = wg & 15;
    const int cg  = wg >> 4;          // 0..7 (teammates stride 16 -> same XCD)

    const int brow0 = bg * 2;
    const int len0 = lengths[brow0], len1 = lengths[brow0 + 1];
    const int tmax = max(len0, len1);

    // GEMV mapping: q = k-quarter, cl = local col in [0,128)
    const int q   = tid >> 7;
    const int cl  = tid & 127;
    const int g0  = cl >> 5;
    const int dd0 = cl & 31;
    const int gcol = g0 * 256 + cg * 32 + dd0;    // global column
    const int q64 = q * 64;

    // persistent W slices, both dirs: 128 floats (constant indices only!)
    float wf[64], wb[64];
    {
        const float* wpf = Whf + (size_t)q64 * G4_ + gcol;
        const float* wpb = Whb + (size_t)q64 * G4_ + gcol;
#define LOADW(k) wf[k] = wpf[(size_t)(k) * G4_]; wb[k] = wpb[(size_t)(k) * G4_];
        RPT64(LOADW)
#undef LOADW
    }

    // gate mapping (tid < 64): row gr, local hidden index gd
    const int gr    = tid >> 5;
    const int gd    = tid & 31;
    const int gbrow = brow0 + gr;
    const int glen  = gr ? len1 : len0;
    float cst0 = 0.f, hreg0 = 0.f, pacc0 = 0.f;
    float cst1 = 0.f, hreg1 = 0.f, pacc1 = 0.f;

    // h-packet loader mapping (all 512 threads): row lrow, index ld
    const int lrow = tid >> 8;
    const int ld   = tid & 255;
    const size_t bufStride = (size_t)2 * B_ * H_;   // packets per parity
    unsigned long long* slotR0 = hx + ((size_t)(brow0 + lrow)) * 256 + ld;
    unsigned long long* slotR1 = slotR0 + (size_t)B_ * H_;
    unsigned long long* slotW0 = hx + (size_t)gbrow * 256 + cg * 32 + gd;
    unsigned long long* slotW1 = slotW0 + (size_t)B_ * H_;

    for (int s = 0; s < tmax; ++s) {
        const int tt0 = s;
        const int tt1 = tmax - 1 - s;
        const size_t par = (size_t)(s & 1) * bufStride;

        // prefetch BOTH dirs' packets + P rows up front (loads overlap)
        const unsigned long long* sp0 = slotR0 + par;
        const unsigned long long* sp1 = slotR1 + par;
        unsigned long long pk0 = __hip_atomic_load(sp0, __ATOMIC_RELAXED,
                                                   __HIP_MEMORY_SCOPE_AGENT);
        unsigned long long pk1 = __hip_atomic_load(sp1, __ATOMIC_RELAXED,
                                                   __HIP_MEMORY_SCOPE_AGENT);
        float pv00 = 0.f, pv01 = 0.f, pv02 = 0.f, pv03 = 0.f;
        float pv10 = 0.f, pv11 = 0.f, pv12 = 0.f, pv13 = 0.f;
        if (tid < 64) {
            const float* pr0 = Pf + (size_t)(gbrow * T_ + tt0) * G4_ + cg * 32 + gd;
            const float* pr1 = Pb + (size_t)(gbrow * T_ + tt1) * G4_ + cg * 32 + gd;
            pv00 = pr0[0]; pv01 = pr0[256]; pv02 = pr0[512]; pv03 = pr0[768];
            pv10 = pr1[0]; pv11 = pr1[256]; pv12 = pr1[512]; pv13 = pr1[768];
        }

        // ---------------- dir 0 (forward) ----------------
        while ((unsigned)(pk0 >> 32) < (unsigned)s) {
            __builtin_amdgcn_s_sleep(1);
            pk0 = __hip_atomic_load(sp0, __ATOMIC_RELAXED,
                                    __HIP_MEMORY_SCOPE_AGENT);
        }
        h_sh[0][lrow][ld] = __uint_as_float((unsigned)pk0);
        __syncthreads();
        {
            const float* h0 = &h_sh[0][0][q64];
            const float* h1 = &h_sh[0][1][q64];
            float a0 = 0.f, a1 = 0.f;
#define GEMV4F(k4) { \
            const float4 hv0 = *(const float4*)(h0 + 4 * (k4)); \
            const float4 hv1 = *(const float4*)(h1 + 4 * (k4)); \
            a0 += hv0.x * wf[4*(k4)  ]; a1 += hv1.x * wf[4*(k4)  ]; \
            a0 += hv0.y * wf[4*(k4)+1]; a1 += hv1.y * wf[4*(k4)+1]; \
            a0 += hv0.z * wf[4*(k4)+2]; a1 += hv1.z * wf[4*(k4)+2]; \
            a0 += hv0.w * wf[4*(k4)+3]; a1 += hv1.w * wf[4*(k4)+3]; }
            RPT16(GEMV4F, 0)
#undef GEMV4F
            zp[0][q][0][cl] = a0;
            zp[0][q][1][cl] = a1;
        }
        __syncthreads();
        if (tid < 64) {
            float zi = pv00 + zp[0][0][gr][gd]      + zp[0][1][gr][gd]      + zp[0][2][gr][gd]      + zp[0][3][gr][gd];
            float zf = pv01 + zp[0][0][gr][32 + gd] + zp[0][1][gr][32 + gd] + zp[0][2][gr][32 + gd] + zp[0][3][gr][32 + gd];
            float zg = pv02 + zp[0][0][gr][64 + gd] + zp[0][1][gr][64 + gd] + zp[0][2][gr][64 + gd] + zp[0][3][gr][64 + gd];
            float zo = pv03 + zp[0][0][gr][96 + gd] + zp[0][1][gr][96 + gd] + zp[0][2][gr][96 + gd] + zp[0][3][gr][96 + gd];
            const float ig = fsigm(zi);
            const float fg = fsigm(zf);
            const float gg = ftanh(zg);
            const float og = fsigm(zo);
            const float cn = fg * cst0 + ig * gg;
            const float hn = og * ftanh(cn);
            if (tt0 < glen) { cst0 = cn; hreg0 = hn; pacc0 += hn; }
            const unsigned long long opk =
                ((unsigned long long)(unsigned)(s + 1) << 32) |
                (unsigned long long)__float_as_uint(hreg0);
            __hip_atomic_store(slotW0 + (size_t)((s + 1) & 1) * bufStride, opk,
                               __ATOMIC_RELAXED, __HIP_MEMORY_SCOPE_AGENT);
        }

        // ---------------- dir 1 (backward) ----------------
        while ((unsigned)(pk1 >> 32) < (unsigned)s) {
            __builtin_amdgcn_s_sleep(1);
            pk1 = __hip_atomic_load(sp1, __ATOMIC_RELAXED,
                                    __HIP_MEMORY_SCOPE_AGENT);
        }
        h_sh[1][lrow][ld] = __uint_as_float((unsigned)pk1);
        __syncthreads();
        {
            const float* h0 = &h_sh[1][0][q64];
            const float* h1 = &h_sh[1][1][q64];
            float a0 = 0.f, a1 = 0.f;
#define GEMV4B(k4) { \
            const float4 hv0 = *(const float4*)(h0 + 4 * (k4)); \
            const float4 hv1 = *(const float4*)(h1 + 4 * (k4)); \
            a0 += hv0.x * wb[4*(k4)  ]; a1 += hv1.x * wb[4*(k4)  ]; \
            a0 += hv0.y * wb[4*(k4)+1]; a1 += hv1.y * wb[4*(k4)+1]; \
            a0 += hv0.z * wb[4*(k4)+2]; a1 += hv1.z * wb[4*(k4)+2]; \
            a0 += hv0.w * wb[4*(k4)+3]; a1 += hv1.w * wb[4*(k4)+3]; }
            RPT16(GEMV4B, 0)
#undef GEMV4B
            zp[1][q][0][cl] = a0;
            zp[1][q][1][cl] = a1;
        }
        __syncthreads();
        if (tid < 64) {
            float zi = pv10 + zp[1][0][gr][gd]      + zp[1][1][gr][gd]      + zp[1][2][gr][gd]      + zp[1][3][gr][gd];
            float zf = pv11 + zp[1][0][gr][32 + gd] + zp[1][1][gr][32 + gd] + zp[1][2][gr][32 + gd] + zp[1][3][gr][32 + gd];
            float zg = pv12 + zp[1][0][gr][64 + gd] + zp[1][1][gr][64 + gd] + zp[1][2][gr][64 + gd] + zp[1][3][gr][64 + gd];
            float zo = pv13 + zp[1][0][gr][96 + gd] + zp[1][1][gr][96 + gd] + zp[1][2][gr][96 + gd] + zp[1][3][gr][96 + gd];
            const float ig = fsigm(zi);
            const float fg = fsigm(zf);
            const float gg = ftanh(zg);
            const float og = fsigm(zo);
            const float cn = fg * cst1 + ig * gg;
            const float hn = og * ftanh(cn);
            if (tt1 < glen) { cst1 = cn; hreg1 = hn; pacc1 += hn; }
            const unsigned long long opk =
                ((unsigned long long)(unsigned)(s + 1) << 32) |
                (unsigned long long)__float_as_uint(hreg1);
            __hip_atomic_store(slotW1 + (size_t)((s + 1) & 1) * bufStride, opk,
                               __ATOMIC_RELAXED, __HIP_MEMORY_SCOPE_AGENT);
        }
        // no trailing barrier: each dir's zp/h_sh is rewritten only after a
        // subsequent __syncthreads that gate threads reach after their reads.
    }

    if (tid < 64) {
        pool[gbrow * 512 + 0   + cg * 32 + gd] = pacc0 / (float)glen;
        pool[gbrow * 512 + 256 + cg * 32 + gd] = pacc1 / (float)glen;
    }
}

// ---------------------------------------------------------------------------
// Kernel 4: fc_hidden = relu(pool @ Wfc + bfc); out = fc_hidden @ Wout + bout
// ---------------------------------------------------------------------------
__global__ __launch_bounds__(256)
void k_fc(const float* __restrict__ pool, const float* __restrict__ Wfc,
          const float* __restrict__ bfc, const float* __restrict__ Wout,
          const float* __restrict__ bout, float* __restrict__ out)
{
    __shared__ float p_sh[512];
    __shared__ float red[8];

    const int tid = threadIdx.x;
    const int b   = blockIdx.x;

    p_sh[tid]       = pool[b * 512 + tid];
    p_sh[256 + tid] = pool[b * 512 + 256 + tid];
    __syncthreads();

    float acc = bfc[tid];
#pragma unroll 8
    for (int k = 0; k < 512; ++k)
        acc += p_sh[k] * Wfc[(size_t)k * H_ + tid];
    const float fh = fmaxf(acc, 0.f);

    float p0 = fh * Wout[tid * 2 + 0];
    float p1 = fh * Wout[tid * 2 + 1];
#pragma unroll
    for (int off = 32; off > 0; off >>= 1) {
        p0 += __shfl_down(p0, off);
        p1 += __shfl_down(p1, off);
    }
    const int wave = tid >> 6;
    if ((tid & 63) == 0) { red[wave * 2] = p0; red[wave * 2 + 1] = p1; }
    __syncthreads();
    if (tid == 0) {
        out[b * 2 + 0] = red[0] + red[2] + red[4] + red[6] + bout[0];
        out[b * 2 + 1] = red[1] + red[3] + red[5] + red[7] + bout[1];
    }
}

__global__ void k_sentinel(float* out, int n)
{
    const int i = blockIdx.x * blockDim.x + threadIdx.x;
    if (i < n) out[i] = 1.0e9f;
}

extern "C" void kernel_launch(void* const* d_in, const int* in_sizes, int n_in,
                              void* d_out, int out_size, void* d_ws, size_t ws_size,
                              hipStream_t stream)
{
    const float* emb  = (const float*)d_in[0];
    const float* Win  = (const float*)d_in[1];
    const float* bin  = (const float*)d_in[2];
    const float* Wihf = (const float*)d_in[3];
    const float* Whhf = (const float*)d_in[4];
    const float* blf  = (const float*)d_in[5];
    const float* Wihb = (const float*)d_in[6];
    const float* Whhb = (const float*)d_in[7];
    const float* blb  = (const float*)d_in[8];
    const float* Wfc  = (const float*)d_in[9];
    const float* bfc  = (const float*)d_in[10];
    const float* Wout = (const float*)d_in[11];
    const float* bout = (const float*)d_in[12];
    const int*   x    = (const int*)d_in[13];
    const int*   lens = (const int*)d_in[15];
    float*       out  = (float*)d_out;

    const size_t need = ((size_t)M_ * H_ + 2 * (size_t)M_ * G4_) * sizeof(float);
    if (ws_size < need) {
        hipLaunchKernelGGL(k_sentinel, dim3(1), dim3(64), 0, stream, out, out_size);
        return;
    }

    float* z  = (float*)d_ws;                    // [16384,256] (dead after k2)
    float* Pf = z + (size_t)M_ * H_;             // [16384,1024]
    float* Pb = Pf + (size_t)M_ * G4_;           // [16384,1024]

    // overlay inside z region (init runs after k2 has consumed z)
    unsigned long long* hx   = (unsigned long long*)d_ws;        // packets
    float*              pool = (float*)(hx + HXN);               // [32][512]

    hipLaunchKernelGGL(k_embed_proj, dim3(2, 128), dim3(256), 0, stream,
                       emb, Win, bin, x, z);
    hipLaunchKernelGGL(k_in_proj, dim3(8, 128, 2), dim3(256), 0, stream,
                       z, Wihf, blf, Wihb, blb, Pf, Pb);
    hipLaunchKernelGGL(k_init, dim3(128), dim3(256), 0, stream, hx);
    hipLaunchKernelGGL(k_lstm_persist, dim3(NWG), dim3(THR), 0, stream,
                       Pf, Pb, Whhf, Whhb, lens, hx, pool);
    hipLaunchKernelGGL(k_fc, dim3(32), dim3(256), 0, stream,
                       pool, Wfc, bfc, Wout, bout, out);
}